// Round 9
// baseline (6062.214 us; speedup 1.0000x reference)
//
#include <hip/hip_runtime.h>
#include <hip/hip_bf16.h>

typedef float f32x4 __attribute__((ext_vector_type(4)));
typedef short bf16x8 __attribute__((ext_vector_type(8)));
typedef unsigned int u32x4 __attribute__((ext_vector_type(4)));

#define MFMA16x32(a,b,c) __builtin_amdgcn_mfma_f32_16x16x32_bf16((a),(b),(c),0,0,0)

__device__ __forceinline__ unsigned short f2bf(float f) {
  unsigned u = __float_as_uint(f);
  u += 0x7fffu + ((u >> 16) & 1u);
  return (unsigned short)(u >> 16);
}

// H stores: relaxed agent-scope = write-through past L2 into L3 (no dirty L2
// lines). vmcnt(0) ack => globally visible. Proven R6-R8.
__device__ __forceinline__ void ast16(unsigned short* p, unsigned short v) {
  __hip_atomic_store(p, v, __ATOMIC_RELAXED, __HIP_MEMORY_SCOPE_AGENT);
}

// L1/L2-bypass 16B load (reads the L3 coherence point directly; pipelined).
__device__ __forceinline__ u32x4 ld16_bypass(const void* p) {
  u32x4 r;
  asm volatile("global_load_dwordx4 %0, %1, off sc0 sc1" : "=v"(r) : "v"(p) : "memory");
  return r;
}

// ---------------- workspace layout (bytes) ----------------
#define WS_G1BLOB 0ull
#define WS_G3BLOB 8388608ull
#define WS_WOUTT  25165824ull
#define WS_H1RING 33554432ull
#define WS_SYNC   34078720ull
#define WS_H2ALL  34095104ull

#define SLSTRIDE 16   // u32 per sync slot (one 64B line per block)

__global__ void k_init(unsigned* __restrict__ p, int n) {
  int i = blockIdx.x * blockDim.x + threadIdx.x;
  for (; i < n; i += gridDim.x * blockDim.x) p[i] = 0u;
}

// ---------------- pack W1h into per-wave B-fragment blob ----------------
__global__ void k_pack_g1(const float* __restrict__ W1, unsigned short* __restrict__ blob) {
  int gtid = blockIdx.x * 256 + threadIdx.x;      // 524288 threads
  int lane = gtid & 63, kk = (gtid >> 6) & 31, w = gtid >> 11;
  int c = lane & 15, q = lane >> 4;
  int g = c >> 2, h = w * 4 + (c & 3);
  bf16x8 s;
#pragma unroll
  for (int j = 0; j < 8; ++j) {
    int k = kk * 32 + q * 8 + j;
    float v = W1[(size_t)g * 5242880u + (size_t)(4096 + k) * 1024u + h];
    ((unsigned short*)&s)[j] = f2bf(v);
  }
  ((bf16x8*)blob)[(size_t)(w * 32 + kk) * 64 + lane] = s;
}

// ---------------- pack W2 (kk<32 -> W2h rows 1024+, kk>=32 -> W2x rows 0..1023) ----------------
__global__ void k_pack_g3(const float* __restrict__ W2, unsigned short* __restrict__ blob) {
  int gtid = blockIdx.x * 256 + threadIdx.x;      // 1048576 threads
  int lane = gtid & 63, kk = (gtid >> 6) & 63, w = gtid >> 12;
  int c = lane & 15, q = lane >> 4;
  int g = c >> 2, h = w * 4 + (c & 3);
  bf16x8 s;
#pragma unroll
  for (int j = 0; j < 8; ++j) {
    int klocal = (kk & 31) * 32 + q * 8 + j;
    int d = (kk < 32) ? (1024 + klocal) : klocal;
    float v = W2[(size_t)g * 2097152u + (size_t)d * 1024u + h];
    ((unsigned short*)&s)[j] = f2bf(v);
  }
  ((bf16x8*)blob)[(size_t)(w * 64 + kk) * 64 + lane] = s;
}

// ---------------- Wout^T bf16 ----------------
__global__ void k_pack_woutT(const float* __restrict__ Wout, unsigned short* __restrict__ wT) {
  int gtid = blockIdx.x * 256 + threadIdx.x;      // 4,194,304 threads
  int k = gtid & 1023, n = gtid >> 10;
  wT[(size_t)n * 1024 + k] = f2bf(Wout[(size_t)k * 4096 + n]);
}

// ---------------- flag-array sync (fence-free) ----------------
__device__ __forceinline__ void poll64(const unsigned* __restrict__ slots,
                                       unsigned epoch, unsigned* __restrict__ poison) {
  unsigned guard = 0;
  for (;;) {
    unsigned v = __hip_atomic_load(&slots[(threadIdx.x & 63) * SLSTRIDE],
                                   __ATOMIC_RELAXED, __HIP_MEMORY_SCOPE_AGENT);
    if (__all((int)(v >= epoch))) break;
    __builtin_amdgcn_s_sleep(1);
    if (((++guard) & 1023u) == 0u) {
      if (guard > (1u << 18) ||
          __hip_atomic_load(poison, __ATOMIC_RELAXED, __HIP_MEMORY_SCOPE_AGENT) != 0u) {
        __hip_atomic_store(poison, 1u, __ATOMIC_RELAXED, __HIP_MEMORY_SCOPE_AGENT);
        break;   // fail-visible, never hard-hang
      }
    }
  }
}

// Merged dual wait: wave0 polls array A, wave1 polls array B, concurrently.
__device__ __forceinline__ void wait_two(const unsigned* sA, unsigned eA,
                                         const unsigned* sB, unsigned eB,
                                         unsigned* poison) {
  const int wv = threadIdx.x >> 6;
  if (wv == 0)      poll64(sA, eA, poison);
  else if (wv == 1) poll64(sB, eB, poison);
  __syncthreads();
}

// Publish: drain write-through stores (=> visible at L3), block barrier, flag store.
__device__ __forceinline__ void publish_slot(unsigned* __restrict__ slots,
                                             int myslot, unsigned epoch) {
  asm volatile("s_waitcnt vmcnt(0)" ::: "memory");
  __syncthreads();
  if (threadIdx.x == 0) {
    __hip_atomic_store(&slots[myslot * SLSTRIDE], epoch,
                       __ATOMIC_RELAXED, __HIP_MEMORY_SCOPE_AGENT);
  }
}

// ---------------- stage 128KB H matrix global->LDS: PIPELINED bypass loads ----
// Rolling window of 16 outstanding loads (counted vmcnt) -> ~1 L3 RTT exposed.
// LDS byte P holds H[row][ (P&2047) ^ ((row&7)<<4) ] (swizzle in SOURCE addr).
__device__ __forceinline__ void stage_H(const unsigned short* __restrict__ Hsrc,
                                        unsigned short* __restrict__ Hs) {
  asm volatile("s_waitcnt vmcnt(0)" ::: "memory");   // isolate counted window
  const int tid = threadIdx.x;
  const char* base = (const char*)Hsrc;
  const int rowlo = tid >> 7;          // 0 or 1
  const int x = (tid & 127) * 16;      // byte col within row
  u32x4 v[4][8];
#define ISSUE_BATCH(B) \
  _Pragma("unroll") \
  for (int r8 = 0; r8 < 8; ++r8) { \
    int row = ((B) * 8 + r8) * 2 + rowlo; \
    v[B][r8] = ld16_bypass(base + row * 2048 + (x ^ ((row & 7) << 4))); \
  }
#define WRITE_BATCH(B) \
  _Pragma("unroll") \
  for (int r8 = 0; r8 < 8; ++r8) \
    *(u32x4*)((char*)Hs + ((B) * 8 + r8) * 4096 + tid * 16) = v[B][r8];

  ISSUE_BATCH(0)
  ISSUE_BATCH(1)                                  // 16 outstanding
  asm volatile("s_waitcnt vmcnt(8)" ::: "memory");  // batch0 done
  __builtin_amdgcn_sched_barrier(0);
  WRITE_BATCH(0)
  ISSUE_BATCH(2)                                  // 16 outstanding
  asm volatile("s_waitcnt vmcnt(8)" ::: "memory");  // batch1 done
  __builtin_amdgcn_sched_barrier(0);
  WRITE_BATCH(1)
  ISSUE_BATCH(3)                                  // 16 outstanding
  asm volatile("s_waitcnt vmcnt(8)" ::: "memory");  // batch2 done
  __builtin_amdgcn_sched_barrier(0);
  WRITE_BATCH(2)
  asm volatile("s_waitcnt vmcnt(0)" ::: "memory");  // batch3 done
  __builtin_amdgcn_sched_barrier(0);
  WRITE_BATCH(3)
#undef ISSUE_BATCH
#undef WRITE_BATCH
}

// swizzled LDS fragment read: row, colb(bytes) -> bf16x8 (ds_read_b128)
__device__ __forceinline__ bf16x8 lds_frag(const unsigned short* __restrict__ Hs,
                                           int row, int colb) {
  return *(const bf16x8*)((const char*)Hs + row * 2048 + (colb ^ ((row & 7) << 4)));
}

// ---------------- persistent recurrent kernel (128 blocks, two decoupled groups) ----------------
// G1 (blocks 0..63):  H1(t) = ew(gather + H1(t-1)@W1h + b1) -> h1ring[t&3]
// G3 (blocks 64..127): H2(t) = ew(b2 + H2(t-1)@W2h + H1(t)@W2x) -> h2all[t]
__global__ __launch_bounds__(256, 1) void k_lstm(
    const int* __restrict__ tokens, const float* __restrict__ W1,
    const float* __restrict__ b1, const float* __restrict__ b2,
    const unsigned short* __restrict__ g1blob, const unsigned short* __restrict__ g3blob,
    unsigned short* __restrict__ h1ring, unsigned short* __restrict__ h2all,
    float* __restrict__ outF, unsigned* __restrict__ syncbase)
{
  __shared__ unsigned short Hs[65536];   // 128 KB staging buffer

  const int tid = threadIdx.x, lane = tid & 63, widx = tid >> 6, bid = blockIdx.x;
  const int c = lane & 15, q = lane >> 4;
  const bool isG1 = bid < 64;
  const int myslot = isG1 ? bid : bid - 64;
  const int w = myslot * 4 + widx;                    // 0..255 within role
  const int g = c >> 2;
  const int hcol = w * 4 + (c & 3);
  const int h_ew = w * 4 + (lane & 3);

  unsigned* g1slots = syncbase;                       // 64 x 16 u32
  unsigned* g3slots = syncbase + 1024;
  unsigned* poison  = syncbase + 2048;

  // --- preload weight fragments into registers ---
  bf16x8 Breg[64];
  {
    const bf16x8* blob1 = (const bf16x8*)g1blob;
    const bf16x8* blob3 = (const bf16x8*)g3blob;
#pragma unroll
    for (int kk = 0; kk < 32; ++kk)
      Breg[kk] = isG1 ? blob1[(size_t)(w * 32 + kk) * 64 + lane]
                      : blob3[(size_t)(w * 64 + kk) * 64 + lane];
    if (!isG1) {
#pragma unroll
      for (int kk = 32; kk < 64; ++kk)
        Breg[kk] = blob3[(size_t)(w * 64 + kk) * 64 + lane];
    }
  }
  const float biasv = isG1 ? b1[g * 1024 + hcol] : b2[g * 1024 + hcol];

  float Cst[16];
#pragma unroll
  for (int i = 0; i < 16; ++i) Cst[i] = 0.f;

  // --- G1: preload embedding gathers for t=0 ---
  float gv[16];
  int tk2[16];
  if (isG1) {
#pragma unroll
    for (int m = 0; m < 4; ++m)
#pragma unroll
      for (int r = 0; r < 4; ++r) {
        int b_ = m * 16 + q * 4 + r;
        int tk = tokens[b_ * 256];
        gv[m * 4 + r] = W1[(size_t)g * 5242880u + (size_t)tk * 1024u + hcol];
      }
  }

  f32x4 acc[4];

  if (isG1) {
    // ================= G1 chain =================
#pragma clang loop unroll(disable)
    for (int t = 0; t < 256; ++t) {
      // merged: own-group barrier + ring backpressure, polled concurrently
      wait_two(g1slots, (unsigned)t, g3slots, (unsigned)(t > 3 ? t - 3 : 0), poison);

      // tokens for step t+1 (consumed by gather prefetch after publish)
      const int tn = (t < 255) ? t + 1 : 255;
#pragma unroll
      for (int m = 0; m < 4; ++m)
#pragma unroll
        for (int r = 0; r < 4; ++r)
          tk2[m * 4 + r] = tokens[(m * 16 + q * 4 + r) * 256 + tn];

#pragma unroll
      for (int m = 0; m < 4; ++m) acc[m] = (f32x4){0.f, 0.f, 0.f, 0.f};
      if (t > 0) {
        stage_H(h1ring + ((t - 1) & 3) * 65536, Hs);
        __syncthreads();
#pragma unroll
        for (int kk = 0; kk < 32; ++kk) {
#pragma unroll
          for (int m = 0; m < 4; ++m) {
            bf16x8 a = lds_frag(Hs, m * 16 + c, kk * 64 + q * 16);
            acc[m] = MFMA16x32(a, Breg[kk], acc[m]);
          }
        }
        __syncthreads();   // Hs reads done before next step's staging
      }

#pragma unroll
      for (int m = 0; m < 4; ++m) {
#pragma unroll
        for (int r = 0; r < 4; ++r) {
          float v = acc[m][r] + gv[m * 4 + r] + biasv;
          const int sb = (lane & 48) | (lane & 3);
          float vf = __shfl(v, sb, 64);
          float vi = __shfl(v, sb | 4, 64);
          float vo = __shfl(v, sb | 8, 64);
          float vc = __shfl(v, sb | 12, 64);
          float fg = 1.f / (1.f + __expf(-vf));
          float ig = 1.f / (1.f + __expf(-vi));
          float og = 1.f / (1.f + __expf(-vo));
          float e2 = __expf(2.f * vc);
          float ct = (e2 - 1.f) / (e2 + 1.f);
          float Cn = fg * Cst[m * 4 + r] + ig * ct;
          Cst[m * 4 + r] = Cn;
          float e2c = __expf(2.f * Cn);
          float Hn = og * (e2c - 1.f) / (e2c + 1.f);
          if ((lane & 12) == 0) {
            int row = m * 16 + q * 4 + r;
            ast16(&h1ring[(t & 3) * 65536 + row * 1024 + h_ew], f2bf(Hn));
            if (t == 255) {
              outF[row * 1024 + h_ew] = Hn;           // H1 final
              outF[65536 + row * 1024 + h_ew] = Cn;   // C1 final
            }
          }
        }
      }
      publish_slot(g1slots, myslot, (unsigned)(t + 1));      // H1(t) published

      // prefetch next step's embedding gathers (latency hides under next poll)
#pragma unroll
      for (int i = 0; i < 16; ++i)
        gv[i] = W1[(size_t)g * 5242880u + (size_t)tk2[i] * 1024u + hcol];
    }
  } else {
    // ================= G3 chain =================
#pragma clang loop unroll(disable)
    for (int t = 0; t < 256; ++t) {
      // merged: own-group barrier (H2(t-1)) + H1(t) availability, concurrent polls
      wait_two(g3slots, (unsigned)t, g1slots, (unsigned)(t + 1), poison);

#pragma unroll
      for (int m = 0; m < 4; ++m) acc[m] = (f32x4){biasv, biasv, biasv, biasv};

      if (t > 0) {         // phase A: H2(t-1) @ W2h
        stage_H(h2all + (size_t)(t - 1) * 65536, Hs);
        __syncthreads();
#pragma unroll
        for (int kk = 0; kk < 32; ++kk) {
#pragma unroll
          for (int m = 0; m < 4; ++m) {
            bf16x8 a = lds_frag(Hs, m * 16 + c, kk * 64 + q * 16);
            acc[m] = MFMA16x32(a, Breg[kk], acc[m]);
          }
        }
        __syncthreads();
      }

      // phase C: H1(t) @ W2x
      stage_H(h1ring + (t & 3) * 65536, Hs);
      __syncthreads();
#pragma unroll
      for (int kk = 32; kk < 64; ++kk) {
#pragma unroll
        for (int m = 0; m < 4; ++m) {
          bf16x8 a = lds_frag(Hs, m * 16 + c, (kk - 32) * 64 + q * 16);
          acc[m] = MFMA16x32(a, Breg[kk], acc[m]);
        }
      }
      __syncthreads();

#pragma unroll
      for (int m = 0; m < 4; ++m) {
#pragma unroll
        for (int r = 0; r < 4; ++r) {
          float v = acc[m][r];
          const int sb = (lane & 48) | (lane & 3);
          float vf = __shfl(v, sb, 64);
          float vi = __shfl(v, sb | 4, 64);
          float vo = __shfl(v, sb | 8, 64);
          float vc = __shfl(v, sb | 12, 64);
          float fg = 1.f / (1.f + __expf(-vf));
          float ig = 1.f / (1.f + __expf(-vi));
          float og = 1.f / (1.f + __expf(-vo));
          float e2 = __expf(2.f * vc);
          float ct = (e2 - 1.f) / (e2 + 1.f);
          float Cn = fg * Cst[m * 4 + r] + ig * ct;
          Cst[m * 4 + r] = Cn;
          float e2c = __expf(2.f * Cn);
          float Hn = og * (e2c - 1.f) / (e2c + 1.f);
          if ((lane & 12) == 0) {
            int row = m * 16 + q * 4 + r;
            ast16(&h2all[((size_t)t * 64 + row) * 1024 + h_ew], f2bf(Hn));
            if (t == 255) {
              outF[131072 + row * 1024 + h_ew] = Hn;  // H2 final
              outF[196608 + row * 1024 + h_ew] = Cn;  // C2 final
            }
          }
        }
      }
      publish_slot(g3slots, myslot, (unsigned)(t + 1));      // H2(t) published
    }
  }
}

// ---------------- output projection: Y = H2all @ Wout + bout ----------------
__global__ __launch_bounds__(256, 2) void k_gemm_out(
    const unsigned short* __restrict__ A, const unsigned short* __restrict__ Bt,
    const float* __restrict__ bout, float* __restrict__ C)
{
  __shared__ unsigned short As[128 * 32];
  __shared__ unsigned short Bs[128 * 32];
  const int tid = threadIdx.x, lane = tid & 63, wv = tid >> 6;
  const int c = lane & 15, q = lane >> 4;
  const int bn = blockIdx.x & 31, bm = blockIdx.x >> 5;
  const int wm = wv >> 1, wn = wv & 1;

  f32x4 acc[4][4];
#pragma unroll
  for (int m = 0; m < 4; ++m)
#pragma unroll
    for (int n = 0; n < 4; ++n) acc[m][n] = (f32x4){0.f, 0.f, 0.f, 0.f};

  const unsigned short* Abase = A + (size_t)(bm * 128) * 1024;
  const unsigned short* Bbase = Bt + (size_t)(bn * 128) * 1024;

  for (int kt = 0; kt < 32; ++kt) {
    if (kt) __syncthreads();
#pragma unroll
    for (int ch = 0; ch < 2; ++ch) {
      int o = ch * 4096 + tid * 16;          // byte offset within 8KB tile
      int row = o >> 6;
      int ks = (o & 63) >> 1;
      *(bf16x8*)&As[o >> 1] = *(const bf16x8*)(Abase + (size_t)row * 1024 + kt * 32 + ks);
      *(bf16x8*)&Bs[o >> 1] = *(const bf16x8*)(Bbase + (size_t)row * 1024 + kt * 32 + ks);
    }
    __syncthreads();
    bf16x8 af[4], bfr[4];
#pragma unroll
    for (int m = 0; m < 4; ++m) af[m] = *(const bf16x8*)&As[(wm * 64 + m * 16 + c) * 32 + q * 8];
#pragma unroll
    for (int n = 0; n < 4; ++n) bfr[n] = *(const bf16x8*)&Bs[(wn * 64 + n * 16 + c) * 32 + q * 8];
#pragma unroll
    for (int m = 0; m < 4; ++m)
#pragma unroll
      for (int n = 0; n < 4; ++n) acc[m][n] = MFMA16x32(af[m], bfr[n], acc[m][n]);
  }

#pragma unroll
  for (int n = 0; n < 4; ++n) {
    int col = bn * 128 + wn * 64 + n * 16 + c;
    float bo = bout[col];
#pragma unroll
    for (int m = 0; m < 4; ++m) {
      int row0 = bm * 128 + wm * 64 + m * 16 + q * 4;
#pragma unroll
      for (int r = 0; r < 4; ++r)
        C[(size_t)(row0 + r) * 4096 + col] = acc[m][n][r] + bo;
    }
  }
}

extern "C" void kernel_launch(void* const* d_in, const int* in_sizes, int n_in,
                              void* d_out, int out_size, void* d_ws, size_t ws_size,
                              hipStream_t stream) {
  const int* tokens = (const int*)d_in[0];
  const float* W1 = (const float*)d_in[1];
  const float* b1 = (const float*)d_in[2];
  const float* W2 = (const float*)d_in[3];
  const float* b2 = (const float*)d_in[4];
  const float* Wout = (const float*)d_in[5];
  const float* bout = (const float*)d_in[6];

  char* ws = (char*)d_ws;
  unsigned short* g1blob = (unsigned short*)(ws + WS_G1BLOB);
  unsigned short* g3blob = (unsigned short*)(ws + WS_G3BLOB);
  unsigned short* woutT  = (unsigned short*)(ws + WS_WOUTT);
  unsigned short* h1ring = (unsigned short*)(ws + WS_H1RING);
  unsigned*       syncb  = (unsigned*)(ws + WS_SYNC);
  unsigned short* h2all  = (unsigned short*)(ws + WS_H2ALL);

  float* outY = (float*)d_out;
  float* outF = outY + 67108864;   // Y then H1,C1,H2,C2

  hipLaunchKernelGGL(k_init, dim3(16), dim3(256), 0, stream, syncb, 4096);
  hipLaunchKernelGGL(k_pack_g1, dim3(2048), dim3(256), 0, stream, W1, g1blob);
  hipLaunchKernelGGL(k_pack_g3, dim3(4096), dim3(256), 0, stream, W2, g3blob);
  hipLaunchKernelGGL(k_pack_woutT, dim3(16384), dim3(256), 0, stream, Wout, woutT);

  hipLaunchKernelGGL(k_lstm, dim3(128), dim3(256), 0, stream,
                     tokens, W1, b1, b2, g1blob, g3blob, h1ring, h2all, outF, syncb);

  hipLaunchKernelGGL(k_gemm_out, dim3(4096), dim3(256), 0, stream, h2all, woutT, bout, outY);
}

// Round 10
// 4491.680 us; speedup vs baseline: 1.3497x; 1.3497x over previous
//
#include <hip/hip_runtime.h>
#include <hip/hip_bf16.h>

typedef float f32x4 __attribute__((ext_vector_type(4)));
typedef short bf16x8 __attribute__((ext_vector_type(8)));
typedef unsigned int u32x4 __attribute__((ext_vector_type(4)));

#define MFMA16x32(a,b,c) __builtin_amdgcn_mfma_f32_16x16x32_bf16((a),(b),(c),0,0,0)

__device__ __forceinline__ unsigned short f2bf(float f) {
  unsigned u = __float_as_uint(f);
  u += 0x7fffu + ((u >> 16) & 1u);
  return (unsigned short)(u >> 16);
}

// H stores: relaxed agent-scope = write-through past L2 into L3 (no dirty L2
// lines). vmcnt(0) ack => globally visible. Proven R6-R9.
__device__ __forceinline__ void ast16(unsigned short* p, unsigned short v) {
  __hip_atomic_store(p, v, __ATOMIC_RELAXED, __HIP_MEMORY_SCOPE_AGENT);
}

// L1/L2-bypass 16B load (reads the L3 coherence point directly; pipelined).
__device__ __forceinline__ u32x4 ld16_bypass(const void* p) {
  u32x4 r;
  asm volatile("global_load_dwordx4 %0, %1, off sc0 sc1" : "=v"(r) : "v"(p) : "memory");
  return r;
}

// ---------------- workspace layout (bytes) ----------------
#define WS_G1BLOB 0ull
#define WS_G3BLOB 8388608ull
#define WS_WOUTT  25165824ull
#define WS_H1RING 33554432ull
#define WS_SYNC   34078720ull
#define WS_H2ALL  34095104ull

#define SLSTRIDE 16   // u32 per sync slot (one 64B line per block)

__global__ void k_init(unsigned* __restrict__ p, int n) {
  int i = blockIdx.x * blockDim.x + threadIdx.x;
  for (; i < n; i += gridDim.x * blockDim.x) p[i] = 0u;
}

// ---------------- pack W1h into per-wave B-fragment blob ----------------
__global__ void k_pack_g1(const float* __restrict__ W1, unsigned short* __restrict__ blob) {
  int gtid = blockIdx.x * 256 + threadIdx.x;      // 524288 threads
  int lane = gtid & 63, kk = (gtid >> 6) & 31, w = gtid >> 11;
  int c = lane & 15, q = lane >> 4;
  int g = c >> 2, h = w * 4 + (c & 3);
  bf16x8 s;
#pragma unroll
  for (int j = 0; j < 8; ++j) {
    int k = kk * 32 + q * 8 + j;
    float v = W1[(size_t)g * 5242880u + (size_t)(4096 + k) * 1024u + h];
    ((unsigned short*)&s)[j] = f2bf(v);
  }
  ((bf16x8*)blob)[(size_t)(w * 32 + kk) * 64 + lane] = s;
}

// ---------------- pack W2 (kk<32 -> W2h rows 1024+, kk>=32 -> W2x rows 0..1023) ----------------
__global__ void k_pack_g3(const float* __restrict__ W2, unsigned short* __restrict__ blob) {
  int gtid = blockIdx.x * 256 + threadIdx.x;      // 1048576 threads
  int lane = gtid & 63, kk = (gtid >> 6) & 63, w = gtid >> 12;
  int c = lane & 15, q = lane >> 4;
  int g = c >> 2, h = w * 4 + (c & 3);
  bf16x8 s;
#pragma unroll
  for (int j = 0; j < 8; ++j) {
    int klocal = (kk & 31) * 32 + q * 8 + j;
    int d = (kk < 32) ? (1024 + klocal) : klocal;
    float v = W2[(size_t)g * 2097152u + (size_t)d * 1024u + h];
    ((unsigned short*)&s)[j] = f2bf(v);
  }
  ((bf16x8*)blob)[(size_t)(w * 64 + kk) * 64 + lane] = s;
}

// ---------------- Wout^T bf16 ----------------
__global__ void k_pack_woutT(const float* __restrict__ Wout, unsigned short* __restrict__ wT) {
  int gtid = blockIdx.x * 256 + threadIdx.x;      // 4,194,304 threads
  int k = gtid & 1023, n = gtid >> 10;
  wT[(size_t)n * 1024 + k] = f2bf(Wout[(size_t)k * 4096 + n]);
}

// ---------------- flag-array sync (fence-free; R8 structure) ----------------
__device__ __forceinline__ void wait_slots(const unsigned* __restrict__ slots,
                                           unsigned epoch, unsigned* __restrict__ poison) {
  if (threadIdx.x < 64) {
    unsigned guard = 0;
    for (;;) {
      unsigned v = __hip_atomic_load(&slots[threadIdx.x * SLSTRIDE],
                                     __ATOMIC_RELAXED, __HIP_MEMORY_SCOPE_AGENT);
      if (__all((int)(v >= epoch))) break;
      __builtin_amdgcn_s_sleep(1);
      if (((++guard) & 1023u) == 0u) {
        if (guard > (1u << 18) ||
            __hip_atomic_load(poison, __ATOMIC_RELAXED, __HIP_MEMORY_SCOPE_AGENT) != 0u) {
          __hip_atomic_store(poison, 1u, __ATOMIC_RELAXED, __HIP_MEMORY_SCOPE_AGENT);
          break;   // fail-visible, never hard-hang
        }
      }
    }
  }
  __syncthreads();
}

// Publish: drain write-through stores (=> visible at L3), block barrier, flag store.
__device__ __forceinline__ void publish_slot(unsigned* __restrict__ slots,
                                             int myslot, unsigned epoch) {
  asm volatile("s_waitcnt vmcnt(0)" ::: "memory");
  __syncthreads();
  if (threadIdx.x == 0) {
    __hip_atomic_store(&slots[myslot * SLSTRIDE], epoch,
                       __ATOMIC_RELAXED, __HIP_MEMORY_SCOPE_AGENT);
  }
}

// ---------------- stage 128KB H matrix global->LDS: PIPELINED bypass loads ----
// Rolling window of 16 outstanding loads (counted vmcnt) -> ~1 L3 RTT exposed
// instead of 4 serialized RTTs. Entry vmcnt(0) isolates the counted window
// from straggler loads (gathers/flag stores). Proven correct in R9.
// LDS byte P holds H[row][ (P&2047) ^ ((row&7)<<4) ] (swizzle in SOURCE addr).
__device__ __forceinline__ void stage_H(const unsigned short* __restrict__ Hsrc,
                                        unsigned short* __restrict__ Hs) {
  asm volatile("s_waitcnt vmcnt(0)" ::: "memory");   // isolate counted window
  const int tid = threadIdx.x;
  const char* base = (const char*)Hsrc;
  const int rowlo = tid >> 7;          // 0 or 1
  const int x = (tid & 127) * 16;      // byte col within row
  u32x4 v[4][8];
#define ISSUE_BATCH(B) \
  _Pragma("unroll") \
  for (int r8 = 0; r8 < 8; ++r8) { \
    int row = ((B) * 8 + r8) * 2 + rowlo; \
    v[B][r8] = ld16_bypass(base + row * 2048 + (x ^ ((row & 7) << 4))); \
  }
#define WRITE_BATCH(B) \
  _Pragma("unroll") \
  for (int r8 = 0; r8 < 8; ++r8) \
    *(u32x4*)((char*)Hs + ((B) * 8 + r8) * 4096 + tid * 16) = v[B][r8];

  ISSUE_BATCH(0)
  ISSUE_BATCH(1)                                    // 16 outstanding
  asm volatile("s_waitcnt vmcnt(8)" ::: "memory");  // batch0 done
  __builtin_amdgcn_sched_barrier(0);
  WRITE_BATCH(0)
  ISSUE_BATCH(2)
  asm volatile("s_waitcnt vmcnt(8)" ::: "memory");  // batch1 done
  __builtin_amdgcn_sched_barrier(0);
  WRITE_BATCH(1)
  ISSUE_BATCH(3)
  asm volatile("s_waitcnt vmcnt(8)" ::: "memory");  // batch2 done
  __builtin_amdgcn_sched_barrier(0);
  WRITE_BATCH(2)
  asm volatile("s_waitcnt vmcnt(0)" ::: "memory");  // batch3 done
  __builtin_amdgcn_sched_barrier(0);
  WRITE_BATCH(3)
#undef ISSUE_BATCH
#undef WRITE_BATCH
}

// swizzled LDS fragment read: row, colb(bytes) -> bf16x8 (ds_read_b128)
__device__ __forceinline__ bf16x8 lds_frag(const unsigned short* __restrict__ Hs,
                                           int row, int colb) {
  return *(const bf16x8*)((const char*)Hs + row * 2048 + (colb ^ ((row & 7) << 4)));
}

// ---------------- persistent recurrent kernel (128 blocks, two decoupled groups) ----------------
// G1 (blocks 0..63):  H1(t) = ew(gather + H1(t-1)@W1h + b1) -> h1ring[t&3]
// G3 (blocks 64..127): H2(t) = ew(b2 + H1(t)@W2x [EARLY, pre-barrier]
//                                  + H2(t-1)@W2h [post-barrier]) -> h2all[t]
__global__ __launch_bounds__(256, 1) void k_lstm(
    const int* __restrict__ tokens, const float* __restrict__ W1,
    const float* __restrict__ b1, const float* __restrict__ b2,
    const unsigned short* __restrict__ g1blob, const unsigned short* __restrict__ g3blob,
    unsigned short* __restrict__ h1ring, unsigned short* __restrict__ h2all,
    float* __restrict__ outF, unsigned* __restrict__ syncbase)
{
  __shared__ unsigned short Hs[65536];   // 128 KB staging buffer

  const int tid = threadIdx.x, lane = tid & 63, widx = tid >> 6, bid = blockIdx.x;
  const int c = lane & 15, q = lane >> 4;
  const bool isG1 = bid < 64;
  const int myslot = isG1 ? bid : bid - 64;
  const int w = myslot * 4 + widx;                    // 0..255 within role
  const int g = c >> 2;
  const int hcol = w * 4 + (c & 3);
  const int h_ew = w * 4 + (lane & 3);

  unsigned* g1slots = syncbase;                       // 64 x 16 u32
  unsigned* g3slots = syncbase + 1024;
  unsigned* poison  = syncbase + 2048;

  // --- preload weight fragments into registers ---
  bf16x8 Breg[64];
  {
    const bf16x8* blob1 = (const bf16x8*)g1blob;
    const bf16x8* blob3 = (const bf16x8*)g3blob;
#pragma unroll
    for (int kk = 0; kk < 32; ++kk)
      Breg[kk] = isG1 ? blob1[(size_t)(w * 32 + kk) * 64 + lane]
                      : blob3[(size_t)(w * 64 + kk) * 64 + lane];
    if (!isG1) {
#pragma unroll
      for (int kk = 32; kk < 64; ++kk)
        Breg[kk] = blob3[(size_t)(w * 64 + kk) * 64 + lane];
    }
  }
  const float biasv = isG1 ? b1[g * 1024 + hcol] : b2[g * 1024 + hcol];

  float Cst[16];
#pragma unroll
  for (int i = 0; i < 16; ++i) Cst[i] = 0.f;

  // --- G1: preload embedding gathers for t=0 ---
  float gv[16];
  if (isG1) {
#pragma unroll
    for (int m = 0; m < 4; ++m)
#pragma unroll
      for (int r = 0; r < 4; ++r) {
        int b_ = m * 16 + q * 4 + r;
        int tk = tokens[b_ * 256];
        gv[m * 4 + r] = W1[(size_t)g * 5242880u + (size_t)tk * 1024u + hcol];
      }
  }

  f32x4 acc[4];

  if (isG1) {
    // ================= G1 chain =================
#pragma clang loop unroll(disable)
    for (int t = 0; t < 256; ++t) {
      if (t > 0) wait_slots(g1slots, (unsigned)t, poison);   // all H1(t-1) at L3

      int tk2[16];
      const int tn = (t < 255) ? t + 1 : 255;
#pragma unroll
      for (int m = 0; m < 4; ++m)
#pragma unroll
        for (int r = 0; r < 4; ++r)
          tk2[m * 4 + r] = tokens[(m * 16 + q * 4 + r) * 256 + tn];

#pragma unroll
      for (int m = 0; m < 4; ++m) acc[m] = (f32x4){0.f, 0.f, 0.f, 0.f};
      if (t > 0) {
        stage_H(h1ring + ((t - 1) & 3) * 65536, Hs);
        __syncthreads();
#pragma unroll
        for (int kk = 0; kk < 32; ++kk) {
#pragma unroll
          for (int m = 0; m < 4; ++m) {
            bf16x8 a = lds_frag(Hs, m * 16 + c, kk * 64 + q * 16);
            acc[m] = MFMA16x32(a, Breg[kk], acc[m]);
          }
        }
        __syncthreads();   // Hs reads done before next step's staging
      }
      if (t >= 4) wait_slots(g3slots, (unsigned)(t - 3), poison);  // ring backpressure

#pragma unroll
      for (int m = 0; m < 4; ++m) {
#pragma unroll
        for (int r = 0; r < 4; ++r) {
          float v = acc[m][r] + gv[m * 4 + r] + biasv;
          const int sb = (lane & 48) | (lane & 3);
          float vf = __shfl(v, sb, 64);
          float vi = __shfl(v, sb | 4, 64);
          float vo = __shfl(v, sb | 8, 64);
          float vc = __shfl(v, sb | 12, 64);
          float fg = 1.f / (1.f + __expf(-vf));
          float ig = 1.f / (1.f + __expf(-vi));
          float og = 1.f / (1.f + __expf(-vo));
          float e2 = __expf(2.f * vc);
          float ct = (e2 - 1.f) / (e2 + 1.f);
          float Cn = fg * Cst[m * 4 + r] + ig * ct;
          Cst[m * 4 + r] = Cn;
          float e2c = __expf(2.f * Cn);
          float Hn = og * (e2c - 1.f) / (e2c + 1.f);
          if ((lane & 12) == 0) {
            int row = m * 16 + q * 4 + r;
            ast16(&h1ring[(t & 3) * 65536 + row * 1024 + h_ew], f2bf(Hn));
            if (t == 255) {
              outF[row * 1024 + h_ew] = Hn;           // H1 final
              outF[65536 + row * 1024 + h_ew] = Cn;   // C1 final
            }
          }
        }
      }
      publish_slot(g1slots, myslot, (unsigned)(t + 1));      // H1(t) published

      // prefetch next step's embedding gathers (latency hides under next poll)
#pragma unroll
      for (int i = 0; i < 16; ++i)
        gv[i] = W1[(size_t)g * 5242880u + (size_t)tk2[i] * 1024u + hcol];
    }
  } else {
    // ================= G3 chain =================
#pragma clang loop unroll(disable)
    for (int t = 0; t < 256; ++t) {
      // phase C FIRST (early start): H1(t) available since G1 runs ahead;
      // this work overlaps peers still finishing step t-1.
      wait_slots(g1slots, (unsigned)(t + 1), poison);
#pragma unroll
      for (int m = 0; m < 4; ++m) acc[m] = (f32x4){biasv, biasv, biasv, biasv};
      stage_H(h1ring + (t & 3) * 65536, Hs);
      __syncthreads();
#pragma unroll
      for (int kk = 32; kk < 64; ++kk) {
#pragma unroll
        for (int m = 0; m < 4; ++m) {
          bf16x8 a = lds_frag(Hs, m * 16 + c, (kk - 32) * 64 + q * 16);
          acc[m] = MFMA16x32(a, Breg[kk], acc[m]);
        }
      }
      __syncthreads();   // Hs reads done before reuse

      if (t > 0) {       // phase A: H2(t-1) @ W2h (own-group barrier)
        wait_slots(g3slots, (unsigned)t, poison);
        stage_H(h2all + (size_t)(t - 1) * 65536, Hs);
        __syncthreads();
#pragma unroll
        for (int kk = 0; kk < 32; ++kk) {
#pragma unroll
          for (int m = 0; m < 4; ++m) {
            bf16x8 a = lds_frag(Hs, m * 16 + c, kk * 64 + q * 16);
            acc[m] = MFMA16x32(a, Breg[kk], acc[m]);
          }
        }
        __syncthreads();
      }

#pragma unroll
      for (int m = 0; m < 4; ++m) {
#pragma unroll
        for (int r = 0; r < 4; ++r) {
          float v = acc[m][r];
          const int sb = (lane & 48) | (lane & 3);
          float vf = __shfl(v, sb, 64);
          float vi = __shfl(v, sb | 4, 64);
          float vo = __shfl(v, sb | 8, 64);
          float vc = __shfl(v, sb | 12, 64);
          float fg = 1.f / (1.f + __expf(-vf));
          float ig = 1.f / (1.f + __expf(-vi));
          float og = 1.f / (1.f + __expf(-vo));
          float e2 = __expf(2.f * vc);
          float ct = (e2 - 1.f) / (e2 + 1.f);
          float Cn = fg * Cst[m * 4 + r] + ig * ct;
          Cst[m * 4 + r] = Cn;
          float e2c = __expf(2.f * Cn);
          float Hn = og * (e2c - 1.f) / (e2c + 1.f);
          if ((lane & 12) == 0) {
            int row = m * 16 + q * 4 + r;
            ast16(&h2all[((size_t)t * 64 + row) * 1024 + h_ew], f2bf(Hn));
            if (t == 255) {
              outF[131072 + row * 1024 + h_ew] = Hn;  // H2 final
              outF[196608 + row * 1024 + h_ew] = Cn;  // C2 final
            }
          }
        }
      }
      publish_slot(g3slots, myslot, (unsigned)(t + 1));      // H2(t) published
    }
  }
}

// ---------------- output projection: Y = H2all @ Wout + bout ----------------
__global__ __launch_bounds__(256, 2) void k_gemm_out(
    const unsigned short* __restrict__ A, const unsigned short* __restrict__ Bt,
    const float* __restrict__ bout, float* __restrict__ C)
{
  __shared__ unsigned short As[128 * 32];
  __shared__ unsigned short Bs[128 * 32];
  const int tid = threadIdx.x, lane = tid & 63, wv = tid >> 6;
  const int c = lane & 15, q = lane >> 4;
  const int bn = blockIdx.x & 31, bm = blockIdx.x >> 5;
  const int wm = wv >> 1, wn = wv & 1;

  f32x4 acc[4][4];
#pragma unroll
  for (int m = 0; m < 4; ++m)
#pragma unroll
    for (int n = 0; n < 4; ++n) acc[m][n] = (f32x4){0.f, 0.f, 0.f, 0.f};

  const unsigned short* Abase = A + (size_t)(bm * 128) * 1024;
  const unsigned short* Bbase = Bt + (size_t)(bn * 128) * 1024;

  for (int kt = 0; kt < 32; ++kt) {
    if (kt) __syncthreads();
#pragma unroll
    for (int ch = 0; ch < 2; ++ch) {
      int o = ch * 4096 + tid * 16;          // byte offset within 8KB tile
      int row = o >> 6;
      int ks = (o & 63) >> 1;
      *(bf16x8*)&As[o >> 1] = *(const bf16x8*)(Abase + (size_t)row * 1024 + kt * 32 + ks);
      *(bf16x8*)&Bs[o >> 1] = *(const bf16x8*)(Bbase + (size_t)row * 1024 + kt * 32 + ks);
    }
    __syncthreads();
    bf16x8 af[4], bfr[4];
#pragma unroll
    for (int m = 0; m < 4; ++m) af[m] = *(const bf16x8*)&As[(wm * 64 + m * 16 + c) * 32 + q * 8];
#pragma unroll
    for (int n = 0; n < 4; ++n) bfr[n] = *(const bf16x8*)&Bs[(wn * 64 + n * 16 + c) * 32 + q * 8];
#pragma unroll
    for (int m = 0; m < 4; ++m)
#pragma unroll
      for (int n = 0; n < 4; ++n) acc[m][n] = MFMA16x32(af[m], bfr[n], acc[m][n]);
  }

#pragma unroll
  for (int n = 0; n < 4; ++n) {
    int col = bn * 128 + wn * 64 + n * 16 + c;
    float bo = bout[col];
#pragma unroll
    for (int m = 0; m < 4; ++m) {
      int row0 = bm * 128 + wm * 64 + m * 16 + q * 4;
#pragma unroll
      for (int r = 0; r < 4; ++r)
        C[(size_t)(row0 + r) * 4096 + col] = acc[m][n][r] + bo;
    }
  }
}

extern "C" void kernel_launch(void* const* d_in, const int* in_sizes, int n_in,
                              void* d_out, int out_size, void* d_ws, size_t ws_size,
                              hipStream_t stream) {
  const int* tokens = (const int*)d_in[0];
  const float* W1 = (const float*)d_in[1];
  const float* b1 = (const float*)d_in[2];
  const float* W2 = (const float*)d_in[3];
  const float* b2 = (const float*)d_in[4];
  const float* Wout = (const float*)d_in[5];
  const float* bout = (const float*)d_in[6];

  char* ws = (char*)d_ws;
  unsigned short* g1blob = (unsigned short*)(ws + WS_G1BLOB);
  unsigned short* g3blob = (unsigned short*)(ws + WS_G3BLOB);
  unsigned short* woutT  = (unsigned short*)(ws + WS_WOUTT);
  unsigned short* h1ring = (unsigned short*)(ws + WS_H1RING);
  unsigned*       syncb  = (unsigned*)(ws + WS_SYNC);
  unsigned short* h2all  = (unsigned short*)(ws + WS_H2ALL);

  float* outY = (float*)d_out;
  float* outF = outY + 67108864;   // Y then H1,C1,H2,C2

  hipLaunchKernelGGL(k_init, dim3(16), dim3(256), 0, stream, syncb, 4096);
  hipLaunchKernelGGL(k_pack_g1, dim3(2048), dim3(256), 0, stream, W1, g1blob);
  hipLaunchKernelGGL(k_pack_g3, dim3(4096), dim3(256), 0, stream, W2, g3blob);
  hipLaunchKernelGGL(k_pack_woutT, dim3(16384), dim3(256), 0, stream, Wout, woutT);

  hipLaunchKernelGGL(k_lstm, dim3(128), dim3(256), 0, stream,
                     tokens, W1, b1, b2, g1blob, g3blob, h1ring, h2all, outF, syncb);

  hipLaunchKernelGGL(k_gemm_out, dim3(4096), dim3(256), 0, stream, h2all, woutT, bout, outY);
}

// Round 11
// 2767.606 us; speedup vs baseline: 2.1904x; 1.6229x over previous
//
#include <hip/hip_runtime.h>
#include <hip/hip_bf16.h>

typedef float f32x4 __attribute__((ext_vector_type(4)));
typedef short bf16x8 __attribute__((ext_vector_type(8)));
typedef unsigned int u32x4 __attribute__((ext_vector_type(4)));

#define MFMA16x32(a,b,c) __builtin_amdgcn_mfma_f32_16x16x32_bf16((a),(b),(c),0,0,0)

__device__ __forceinline__ unsigned short f2bf(float f) {
  unsigned u = __float_as_uint(f);
  u += 0x7fffu + ((u >> 16) & 1u);
  return (unsigned short)(u >> 16);
}

// H stores: relaxed agent-scope = write-through past L2 into L3 (no dirty L2
// lines). vmcnt(0) ack => globally visible. Proven R6-R10.
__device__ __forceinline__ void ast16(unsigned short* p, unsigned short v) {
  __hip_atomic_store(p, v, __ATOMIC_RELAXED, __HIP_MEMORY_SCOPE_AGENT);
}

// L1/L2-bypass 16B load (reads the L3 coherence point directly; pipelined).
__device__ __forceinline__ u32x4 ld16_bypass(const void* p) {
  u32x4 r;
  asm volatile("global_load_dwordx4 %0, %1, off sc0 sc1" : "=v"(r) : "v"(p) : "memory");
  return r;
}

// ---------------- workspace layout (bytes) ----------------
#define WS_G1BLOB 0ull
#define WS_G3BLOB 8388608ull
#define WS_WOUTT  25165824ull
#define WS_H1RING 33554432ull
#define WS_SYNC   34078720ull
#define WS_H2ALL  34095104ull

#define SLSTRIDE 8   // u32 per sync slot (32B per block; 128 slots/group = 4KB)

__global__ void k_init(unsigned* __restrict__ p, int n) {
  int i = blockIdx.x * blockDim.x + threadIdx.x;
  for (; i < n; i += gridDim.x * blockDim.x) p[i] = 0u;
}

// ---------------- pack W1h into per-wave B-fragment blob ----------------
__global__ void k_pack_g1(const float* __restrict__ W1, unsigned short* __restrict__ blob) {
  int gtid = blockIdx.x * 256 + threadIdx.x;      // 524288 threads
  int lane = gtid & 63, kk = (gtid >> 6) & 31, w = gtid >> 11;
  int c = lane & 15, q = lane >> 4;
  int g = c >> 2, h = w * 4 + (c & 3);
  bf16x8 s;
#pragma unroll
  for (int j = 0; j < 8; ++j) {
    int k = kk * 32 + q * 8 + j;
    float v = W1[(size_t)g * 5242880u + (size_t)(4096 + k) * 1024u + h];
    ((unsigned short*)&s)[j] = f2bf(v);
  }
  ((bf16x8*)blob)[(size_t)(w * 32 + kk) * 64 + lane] = s;
}

// ---------------- pack W2 (kk<32 -> W2h rows 1024+, kk>=32 -> W2x rows 0..1023) ----------------
__global__ void k_pack_g3(const float* __restrict__ W2, unsigned short* __restrict__ blob) {
  int gtid = blockIdx.x * 256 + threadIdx.x;      // 1048576 threads
  int lane = gtid & 63, kk = (gtid >> 6) & 63, w = gtid >> 12;
  int c = lane & 15, q = lane >> 4;
  int g = c >> 2, h = w * 4 + (c & 3);
  bf16x8 s;
#pragma unroll
  for (int j = 0; j < 8; ++j) {
    int klocal = (kk & 31) * 32 + q * 8 + j;
    int d = (kk < 32) ? (1024 + klocal) : klocal;
    float v = W2[(size_t)g * 2097152u + (size_t)d * 1024u + h];
    ((unsigned short*)&s)[j] = f2bf(v);
  }
  ((bf16x8*)blob)[(size_t)(w * 64 + kk) * 64 + lane] = s;
}

// ---------------- Wout^T bf16 ----------------
__global__ void k_pack_woutT(const float* __restrict__ Wout, unsigned short* __restrict__ wT) {
  int gtid = blockIdx.x * 256 + threadIdx.x;      // 4,194,304 threads
  int k = gtid & 1023, n = gtid >> 10;
  wT[(size_t)n * 1024 + k] = f2bf(Wout[(size_t)k * 4096 + n]);
}

// ---------------- flag-array sync over 128 slots (fence-free) ----------------
// Wave 0: lane i polls slots i and i+64 (RELAXED agent loads), __all over min.
__device__ __forceinline__ void wait_slots(const unsigned* __restrict__ slots,
                                           unsigned epoch, unsigned* __restrict__ poison) {
  if (threadIdx.x < 64) {
    unsigned guard = 0;
    for (;;) {
      unsigned v0 = __hip_atomic_load(&slots[threadIdx.x * SLSTRIDE],
                                      __ATOMIC_RELAXED, __HIP_MEMORY_SCOPE_AGENT);
      unsigned v1 = __hip_atomic_load(&slots[(threadIdx.x + 64) * SLSTRIDE],
                                      __ATOMIC_RELAXED, __HIP_MEMORY_SCOPE_AGENT);
      unsigned v = v0 < v1 ? v0 : v1;
      if (__all((int)(v >= epoch))) break;
      __builtin_amdgcn_s_sleep(1);
      if (((++guard) & 1023u) == 0u) {
        if (guard > (1u << 18) ||
            __hip_atomic_load(poison, __ATOMIC_RELAXED, __HIP_MEMORY_SCOPE_AGENT) != 0u) {
          __hip_atomic_store(poison, 1u, __ATOMIC_RELAXED, __HIP_MEMORY_SCOPE_AGENT);
          break;   // fail-visible, never hard-hang
        }
      }
    }
  }
  __syncthreads();
}

// Publish: drain write-through stores (=> visible at L3), block barrier, flag store.
__device__ __forceinline__ void publish_slot(unsigned* __restrict__ slots,
                                             int myslot, unsigned epoch) {
  asm volatile("s_waitcnt vmcnt(0)" ::: "memory");
  __syncthreads();
  if (threadIdx.x == 0) {
    __hip_atomic_store(&slots[myslot * SLSTRIDE], epoch,
                       __ATOMIC_RELAXED, __HIP_MEMORY_SCOPE_AGENT);
  }
}

// ---------------- stage 128KB H matrix global->LDS: pipelined bypass loads ----
// LDS byte P holds H[row][ (P&2047) ^ ((row&7)<<4) ] (swizzle in SOURCE addr).
__device__ __forceinline__ void stage_H(const unsigned short* __restrict__ Hsrc,
                                        unsigned short* __restrict__ Hs) {
  asm volatile("s_waitcnt vmcnt(0)" ::: "memory");   // isolate counted window
  const int tid = threadIdx.x;
  const char* base = (const char*)Hsrc;
  const int rowlo = tid >> 7;
  const int x = (tid & 127) * 16;
  u32x4 v[4][8];
#define ISSUE_BATCH(B) \
  _Pragma("unroll") \
  for (int r8 = 0; r8 < 8; ++r8) { \
    int row = ((B) * 8 + r8) * 2 + rowlo; \
    v[B][r8] = ld16_bypass(base + row * 2048 + (x ^ ((row & 7) << 4))); \
  }
#define WRITE_BATCH(B) \
  _Pragma("unroll") \
  for (int r8 = 0; r8 < 8; ++r8) \
    *(u32x4*)((char*)Hs + ((B) * 8 + r8) * 4096 + tid * 16) = v[B][r8];

  ISSUE_BATCH(0)
  ISSUE_BATCH(1)
  asm volatile("s_waitcnt vmcnt(8)" ::: "memory");
  __builtin_amdgcn_sched_barrier(0);
  WRITE_BATCH(0)
  ISSUE_BATCH(2)
  asm volatile("s_waitcnt vmcnt(8)" ::: "memory");
  __builtin_amdgcn_sched_barrier(0);
  WRITE_BATCH(1)
  ISSUE_BATCH(3)
  asm volatile("s_waitcnt vmcnt(8)" ::: "memory");
  __builtin_amdgcn_sched_barrier(0);
  WRITE_BATCH(2)
  asm volatile("s_waitcnt vmcnt(0)" ::: "memory");
  __builtin_amdgcn_sched_barrier(0);
  WRITE_BATCH(3)
#undef ISSUE_BATCH
#undef WRITE_BATCH
}

// swizzled LDS fragment read: row, colb(bytes) -> bf16x8 (ds_read_b128)
__device__ __forceinline__ bf16x8 lds_frag(const unsigned short* __restrict__ Hs,
                                           int row, int colb) {
  return *(const bf16x8*)((const char*)Hs + row * 2048 + (colb ^ ((row & 7) << 4)));
}

// ---------------- persistent recurrent kernel: 256 blocks, K-split pairs ----------------
// G1 (blocks 0..127):   H1(t) -> h1ring[t&3].  Block covers 32 cols (2 tiles).
// G3 (blocks 128..255): H2(t) -> h2all[t].
// Within a block: wave widx -> col-tile ct=widx>>1, K-half kh=widx&1.
// Each wave reads only its K-half of H from LDS (halves LDS port traffic);
// partials combined via 8KB LDS reduce; kh==0 waves do elementwise + stores.
__global__ __launch_bounds__(256, 1) void k_lstm(
    const int* __restrict__ tokens, const float* __restrict__ W1,
    const float* __restrict__ b1, const float* __restrict__ b2,
    const unsigned short* __restrict__ g1blob, const unsigned short* __restrict__ g3blob,
    unsigned short* __restrict__ h1ring, unsigned short* __restrict__ h2all,
    float* __restrict__ outF, unsigned* __restrict__ syncbase)
{
  __shared__ unsigned short Hs[65536];   // 128 KB staging buffer
  __shared__ float red[2][64][16];       // 8 KB K-split partial exchange

  const int tid = threadIdx.x, lane = tid & 63, widx = tid >> 6, bid = blockIdx.x;
  const int c = lane & 15, q = lane >> 4;
  const bool isG1 = bid < 128;
  const int myslot = isG1 ? bid : bid - 128;          // 0..127
  const int ct = widx >> 1, kh = widx & 1;
  const int w = myslot * 2 + ct;                      // 0..255 col-unit (16 cols)
  const int g = c >> 2;
  const int hcol = w * 4 + (c & 3);
  const int h_ew = w * 4 + (lane & 3);

  unsigned* g1slots = syncbase;                       // 128 x 8 u32 (4KB)
  unsigned* g3slots = syncbase + 1024;
  unsigned* poison  = syncbase + 2048;

  // --- preload weight fragments (this wave's K-half only) ---
  bf16x8 Breg[32];
  {
    const bf16x8* blob1 = (const bf16x8*)g1blob;
    const bf16x8* blob3 = (const bf16x8*)g3blob;
    if (isG1) {
#pragma unroll
      for (int j = 0; j < 16; ++j)
        Breg[j] = blob1[(size_t)(w * 32 + kh * 16 + j) * 64 + lane];
    } else {
#pragma unroll
      for (int j = 0; j < 16; ++j) {
        Breg[j]      = blob3[(size_t)(w * 64 + kh * 16 + j) * 64 + lane];        // W2h (phase A)
        Breg[16 + j] = blob3[(size_t)(w * 64 + 32 + kh * 16 + j) * 64 + lane];   // W2x (phase C)
      }
    }
  }
  const float biasv = isG1 ? b1[g * 1024 + hcol] : b2[g * 1024 + hcol];

  float Cst[16];
#pragma unroll
  for (int i = 0; i < 16; ++i) Cst[i] = 0.f;

  // --- G1 kh==0: preload embedding gathers for t=0 ---
  float gv[16];
  if (isG1 && kh == 0) {
#pragma unroll
    for (int m = 0; m < 4; ++m)
#pragma unroll
      for (int r = 0; r < 4; ++r) {
        int b_ = m * 16 + q * 4 + r;
        int tk = tokens[b_ * 256];
        gv[m * 4 + r] = W1[(size_t)g * 5242880u + (size_t)tk * 1024u + hcol];
      }
  }

  f32x4 acc[4];

  if (isG1) {
    // ================= G1 chain =================
#pragma clang loop unroll(disable)
    for (int t = 0; t < 256; ++t) {
      if (t > 0) wait_slots(g1slots, (unsigned)t, poison);   // all H1(t-1) at L3

      int tk2[16];
      if (kh == 0) {
        const int tn = (t < 255) ? t + 1 : 255;
#pragma unroll
        for (int m = 0; m < 4; ++m)
#pragma unroll
          for (int r = 0; r < 4; ++r)
            tk2[m * 4 + r] = tokens[(m * 16 + q * 4 + r) * 256 + tn];
      }

#pragma unroll
      for (int m = 0; m < 4; ++m) acc[m] = (f32x4){0.f, 0.f, 0.f, 0.f};
      if (t > 0) {
        stage_H(h1ring + ((t - 1) & 3) * 65536, Hs);
        __syncthreads();
#pragma unroll
        for (int j = 0; j < 16; ++j) {
#pragma unroll
          for (int m = 0; m < 4; ++m) {
            bf16x8 a = lds_frag(Hs, m * 16 + c, (kh * 16 + j) * 64 + q * 16);
            acc[m] = MFMA16x32(a, Breg[j], acc[m]);
          }
        }
      }
      if (t >= 4) wait_slots(g3slots, (unsigned)(t - 3), poison);  // ring backpressure
      else __syncthreads();   // Hs reads done before next stage (uniform barrier)

      // K-split partial exchange
      if (kh == 1) {
#pragma unroll
        for (int m = 0; m < 4; ++m) *(f32x4*)&red[ct][lane][m * 4] = acc[m];
      }
      __syncthreads();
      if (kh == 0) {
#pragma unroll
        for (int m = 0; m < 4; ++m) acc[m] += *(const f32x4*)&red[ct][lane][m * 4];
#pragma unroll
        for (int m = 0; m < 4; ++m) {
#pragma unroll
          for (int r = 0; r < 4; ++r) {
            float v = acc[m][r] + gv[m * 4 + r] + biasv;
            const int sb = (lane & 48) | (lane & 3);
            float vf = __shfl(v, sb, 64);
            float vi = __shfl(v, sb | 4, 64);
            float vo = __shfl(v, sb | 8, 64);
            float vc = __shfl(v, sb | 12, 64);
            float fg = 1.f / (1.f + __expf(-vf));
            float ig = 1.f / (1.f + __expf(-vi));
            float og = 1.f / (1.f + __expf(-vo));
            float e2 = __expf(2.f * vc);
            float ct_ = (e2 - 1.f) / (e2 + 1.f);
            float Cn = fg * Cst[m * 4 + r] + ig * ct_;
            Cst[m * 4 + r] = Cn;
            float e2c = __expf(2.f * Cn);
            float Hn = og * (e2c - 1.f) / (e2c + 1.f);
            if ((lane & 12) == 0) {
              int row = m * 16 + q * 4 + r;
              ast16(&h1ring[(t & 3) * 65536 + row * 1024 + h_ew], f2bf(Hn));
              if (t == 255) {
                outF[row * 1024 + h_ew] = Hn;           // H1 final
                outF[65536 + row * 1024 + h_ew] = Cn;   // C1 final
              }
            }
          }
        }
      }
      publish_slot(g1slots, myslot, (unsigned)(t + 1));      // H1(t) published

      // prefetch next step's embedding gathers (latency hides under next poll)
      if (kh == 0) {
#pragma unroll
        for (int i = 0; i < 16; ++i)
          gv[i] = W1[(size_t)g * 5242880u + (size_t)tk2[i] * 1024u + hcol];
      }
    }
  } else {
    // ================= G3 chain =================
#pragma clang loop unroll(disable)
    for (int t = 0; t < 256; ++t) {
      // phase C FIRST (early start): H1(t) available since G1 runs ahead
      wait_slots(g1slots, (unsigned)(t + 1), poison);
#pragma unroll
      for (int m = 0; m < 4; ++m)
        acc[m] = (kh == 0) ? (f32x4){biasv, biasv, biasv, biasv}
                           : (f32x4){0.f, 0.f, 0.f, 0.f};
      stage_H(h1ring + (t & 3) * 65536, Hs);
      __syncthreads();
#pragma unroll
      for (int j = 0; j < 16; ++j) {
#pragma unroll
        for (int m = 0; m < 4; ++m) {
          bf16x8 a = lds_frag(Hs, m * 16 + c, (kh * 16 + j) * 64 + q * 16);
          acc[m] = MFMA16x32(a, Breg[16 + j], acc[m]);
        }
      }

      if (t > 0) {       // phase A: H2(t-1) @ W2h (own-group barrier guards Hs too)
        wait_slots(g3slots, (unsigned)t, poison);
        stage_H(h2all + (size_t)(t - 1) * 65536, Hs);
        __syncthreads();
#pragma unroll
        for (int j = 0; j < 16; ++j) {
#pragma unroll
          for (int m = 0; m < 4; ++m) {
            bf16x8 a = lds_frag(Hs, m * 16 + c, (kh * 16 + j) * 64 + q * 16);
            acc[m] = MFMA16x32(a, Breg[j], acc[m]);
          }
        }
      }

      // K-split partial exchange
      if (kh == 1) {
#pragma unroll
        for (int m = 0; m < 4; ++m) *(f32x4*)&red[ct][lane][m * 4] = acc[m];
      }
      __syncthreads();
      if (kh == 0) {
#pragma unroll
        for (int m = 0; m < 4; ++m) acc[m] += *(const f32x4*)&red[ct][lane][m * 4];
#pragma unroll
        for (int m = 0; m < 4; ++m) {
#pragma unroll
          for (int r = 0; r < 4; ++r) {
            float v = acc[m][r];
            const int sb = (lane & 48) | (lane & 3);
            float vf = __shfl(v, sb, 64);
            float vi = __shfl(v, sb | 4, 64);
            float vo = __shfl(v, sb | 8, 64);
            float vc = __shfl(v, sb | 12, 64);
            float fg = 1.f / (1.f + __expf(-vf));
            float ig = 1.f / (1.f + __expf(-vi));
            float og = 1.f / (1.f + __expf(-vo));
            float e2 = __expf(2.f * vc);
            float ct_ = (e2 - 1.f) / (e2 + 1.f);
            float Cn = fg * Cst[m * 4 + r] + ig * ct_;
            Cst[m * 4 + r] = Cn;
            float e2c = __expf(2.f * Cn);
            float Hn = og * (e2c - 1.f) / (e2c + 1.f);
            if ((lane & 12) == 0) {
              int row = m * 16 + q * 4 + r;
              ast16(&h2all[((size_t)t * 64 + row) * 1024 + h_ew], f2bf(Hn));
              if (t == 255) {
                outF[131072 + row * 1024 + h_ew] = Hn;  // H2 final
                outF[196608 + row * 1024 + h_ew] = Cn;  // C2 final
              }
            }
          }
        }
      }
      publish_slot(g3slots, myslot, (unsigned)(t + 1));      // H2(t) published
    }
  }
}

// ---------------- output projection: Y = H2all @ Wout + bout ----------------
__global__ __launch_bounds__(256, 2) void k_gemm_out(
    const unsigned short* __restrict__ A, const unsigned short* __restrict__ Bt,
    const float* __restrict__ bout, float* __restrict__ C)
{
  __shared__ unsigned short As[128 * 32];
  __shared__ unsigned short Bs[128 * 32];
  const int tid = threadIdx.x, lane = tid & 63, wv = tid >> 6;
  const int c = lane & 15, q = lane >> 4;
  const int bn = blockIdx.x & 31, bm = blockIdx.x >> 5;
  const int wm = wv >> 1, wn = wv & 1;

  f32x4 acc[4][4];
#pragma unroll
  for (int m = 0; m < 4; ++m)
#pragma unroll
    for (int n = 0; n < 4; ++n) acc[m][n] = (f32x4){0.f, 0.f, 0.f, 0.f};

  const unsigned short* Abase = A + (size_t)(bm * 128) * 1024;
  const unsigned short* Bbase = Bt + (size_t)(bn * 128) * 1024;

  for (int kt = 0; kt < 32; ++kt) {
    if (kt) __syncthreads();
#pragma unroll
    for (int ch = 0; ch < 2; ++ch) {
      int o = ch * 4096 + tid * 16;
      int row = o >> 6;
      int ks = (o & 63) >> 1;
      *(bf16x8*)&As[o >> 1] = *(const bf16x8*)(Abase + (size_t)row * 1024 + kt * 32 + ks);
      *(bf16x8*)&Bs[o >> 1] = *(const bf16x8*)(Bbase + (size_t)row * 1024 + kt * 32 + ks);
    }
    __syncthreads();
    bf16x8 af[4], bfr[4];
#pragma unroll
    for (int m = 0; m < 4; ++m) af[m] = *(const bf16x8*)&As[(wm * 64 + m * 16 + c) * 32 + q * 8];
#pragma unroll
    for (int n = 0; n < 4; ++n) bfr[n] = *(const bf16x8*)&Bs[(wn * 64 + n * 16 + c) * 32 + q * 8];
#pragma unroll
    for (int m = 0; m < 4; ++m)
#pragma unroll
      for (int n = 0; n < 4; ++n) acc[m][n] = MFMA16x32(af[m], bfr[n], acc[m][n]);
  }

#pragma unroll
  for (int n = 0; n < 4; ++n) {
    int col = bn * 128 + wn * 64 + n * 16 + c;
    float bo = bout[col];
#pragma unroll
    for (int m = 0; m < 4; ++m) {
      int row0 = bm * 128 + wm * 64 + m * 16 + q * 4;
#pragma unroll
      for (int r = 0; r < 4; ++r)
        C[(size_t)(row0 + r) * 4096 + col] = acc[m][n][r] + bo;
    }
  }
}

extern "C" void kernel_launch(void* const* d_in, const int* in_sizes, int n_in,
                              void* d_out, int out_size, void* d_ws, size_t ws_size,
                              hipStream_t stream) {
  const int* tokens = (const int*)d_in[0];
  const float* W1 = (const float*)d_in[1];
  const float* b1 = (const float*)d_in[2];
  const float* W2 = (const float*)d_in[3];
  const float* b2 = (const float*)d_in[4];
  const float* Wout = (const float*)d_in[5];
  const float* bout = (const float*)d_in[6];

  char* ws = (char*)d_ws;
  unsigned short* g1blob = (unsigned short*)(ws + WS_G1BLOB);
  unsigned short* g3blob = (unsigned short*)(ws + WS_G3BLOB);
  unsigned short* woutT  = (unsigned short*)(ws + WS_WOUTT);
  unsigned short* h1ring = (unsigned short*)(ws + WS_H1RING);
  unsigned*       syncb  = (unsigned*)(ws + WS_SYNC);
  unsigned short* h2all  = (unsigned short*)(ws + WS_H2ALL);

  float* outY = (float*)d_out;
  float* outF = outY + 67108864;   // Y then H1,C1,H2,C2

  hipLaunchKernelGGL(k_init, dim3(16), dim3(256), 0, stream, syncb, 4096);
  hipLaunchKernelGGL(k_pack_g1, dim3(2048), dim3(256), 0, stream, W1, g1blob);
  hipLaunchKernelGGL(k_pack_g3, dim3(4096), dim3(256), 0, stream, W2, g3blob);
  hipLaunchKernelGGL(k_pack_woutT, dim3(16384), dim3(256), 0, stream, Wout, woutT);

  hipLaunchKernelGGL(k_lstm, dim3(256), dim3(256), 0, stream,
                     tokens, W1, b1, b2, g1blob, g3blob, h1ring, h2all, outF, syncb);

  hipLaunchKernelGGL(k_gemm_out, dim3(4096), dim3(256), 0, stream, h2all, woutT, bout, outY);
}